// Round 12
// baseline (23794.284 us; speedup 1.0000x reference)
//
#include <hip/hip_runtime.h>
#include <math.h>

// Problem constants
#define B_   64
#define U_   1024
#define E_   512
#define D_   640
#define L4_  2560
#define TC   64          // time-chunk length
#define NCH  16          // number of chunks (TC*NCH == U_)
#define NBLK 160         // persistent blocks (4 d's each); 160 <= 256 CUs -> co-resident
#define GRPB 20          // blocks per arrival group (one group per wave k-slice)

// ---------------------------------------------------------------------------
// GEMM: C[t][n][b] = bias[n] + sum_k A[m][k] * W[k][n],  m = t*64 + b
// (unchanged, harness-verified)
// ---------------------------------------------------------------------------
template <int MODE>
__global__ __launch_bounds__(256) void gemm_kernel(
    const float* __restrict__ A,        // MODE0: embed [V][E]; MODE1: h0c [TC][640][64]
    const int*   __restrict__ targets,  // [B][U], used in MODE0
    const float* __restrict__ Wm,       // [K][2560]
    const float* __restrict__ bias,     // [2560]
    float* __restrict__ xz,             // [TC][2560][64]
    int K, int t0)
{
    const int tid = threadIdx.x;
    const int m0 = blockIdx.x * 128;
    const int n0 = blockIdx.y * 128;

    __shared__ float As[8][132];
    __shared__ float Bs[8][132];

    float acc[8][8];
#pragma unroll
    for (int i = 0; i < 8; ++i)
#pragma unroll
        for (int j = 0; j < 8; ++j) acc[i][j] = 0.f;

    const float* a_ptr;
    int a_ml = 0, a_kq = 0, a_k = 0;
    if (MODE == 0) {
        a_ml = tid & 127;
        a_kq = (tid >> 7) * 4;
        int m  = m0 + a_ml;
        int b  = m & 63;
        int tl = m >> 6;
        int idx = targets[b * U_ + t0 + tl];
        a_ptr = A + (size_t)idx * E_ + a_kq;
    } else {
        a_k  = tid >> 5;
        a_ml = (tid & 31) * 4;
        int m  = m0 + a_ml;
        int b  = m & 63;
        int tl = m >> 6;
        a_ptr = A + (size_t)tl * (D_ * 64) + (size_t)a_k * 64 + b;
    }
    const int b_k  = tid >> 5;
    const int b_n4 = (tid & 31) * 4;

    const int tx = tid & 15;
    const int ty = tid >> 4;

    for (int k0 = 0; k0 < K; k0 += 8) {
        if (MODE == 0) {
            float4 av = *(const float4*)(a_ptr + k0);
            As[a_kq + 0][a_ml] = av.x;
            As[a_kq + 1][a_ml] = av.y;
            As[a_kq + 2][a_ml] = av.z;
            As[a_kq + 3][a_ml] = av.w;
        } else {
            float4 av = *(const float4*)(a_ptr + (size_t)k0 * 64);
            *(float4*)&As[a_k][a_ml] = av;
        }
        {
            float4 bv = *(const float4*)(Wm + (size_t)(k0 + b_k) * L4_ + n0 + b_n4);
            *(float4*)&Bs[b_k][b_n4] = bv;
        }
        __syncthreads();

#pragma unroll
        for (int k = 0; k < 8; ++k) {
            float af[8], bf[8];
            *(float4*)&af[0] = *(const float4*)&As[k][ty * 8];
            *(float4*)&af[4] = *(const float4*)&As[k][ty * 8 + 4];
            *(float4*)&bf[0] = *(const float4*)&Bs[k][tx * 8];
            *(float4*)&bf[4] = *(const float4*)&Bs[k][tx * 8 + 4];
#pragma unroll
            for (int i = 0; i < 8; ++i)
#pragma unroll
                for (int j = 0; j < 8; ++j) acc[i][j] += af[i] * bf[j];
        }
        __syncthreads();
    }

#pragma unroll
    for (int i = 0; i < 8; ++i) {
        int m  = m0 + ty * 8 + i;
        int tl = m >> 6;
        int b  = m & 63;
        float* outp = xz + (size_t)tl * (L4_ * 64) + b;
#pragma unroll
        for (int j = 0; j < 8; ++j) {
            int n = n0 + tx * 8 + j;
            outp[(size_t)n * 64] = acc[i][j] + bias[n];
        }
    }
}

// ---------------------------------------------------------------------------
// Pre-transpose recurrent weights, K-MAJOR per block:
//   Up[g][k][n16] = Uw[k][gate*640 + (g*4+dd)],  n16 = dd*4 + gate
// (unchanged from round 10 — harness-verified)
// ---------------------------------------------------------------------------
__global__ __launch_bounds__(256) void prep_up_kernel(
    const float* __restrict__ U0w, const float* __restrict__ U1w,
    float* __restrict__ Up0, float* __restrict__ Up1)
{
    const int k = blockIdx.x;                       // 0..639
    const float* Uw = blockIdx.y ? U1w : U0w;
    float*       Up = blockIdx.y ? Up1 : Up0;
    for (int d = threadIdx.x; d < D_; d += 256) {   // coalesced reads over d
        const int g  = d >> 2;
        const int dd = d & 3;
#pragma unroll
        for (int gate = 0; gate < 4; ++gate) {
            float v = Uw[(size_t)k * L4_ + gate * 640 + d];
            Up[((size_t)g * 640 + k) * 16 + dd * 4 + gate] = v;
        }
    }
}

// ---------------------------------------------------------------------------
// LLC write-through store (sc1, agent scope) — h publish. (r9-r11 verified)
// ---------------------------------------------------------------------------
__device__ __forceinline__ void stg_llc(float* p, float v) {
    __hip_atomic_store(p, v, __ATOMIC_RELAXED, __HIP_MEMORY_SCOPE_AGENT);
}

// ---------------------------------------------------------------------------
// Fine-grained producer-group sync (replaces the global grid barrier).
//  - arrive: after a block's sc1 h-publish drains (vmcnt(0) + syncthreads),
//    thread 0 bumps arr[blockIdx/20] (monotonic LLC RMW, never reset).
//  - wait: wave ks spins until arr[ks] >= 20*(base+tl) — its 20 producer
//    blocks (d-range == its k-slice) have published h(tl-1). One LLC hop,
//    no master level, waves proceed independently (block re-syncs at red[]).
//  - no WAR hazard: h lives at per-step-unique addresses (hc_out chain).
//  - deadlock-free: all 160 blocks co-resident; per-step dependency DAG is
//    the same as the global barrier's, just finer.
// ---------------------------------------------------------------------------
__device__ __forceinline__ void wait_group(const unsigned* arr, int g, unsigned tgt)
{
    while (__hip_atomic_load(arr + (g << 5), __ATOMIC_RELAXED, __HIP_MEMORY_SCOPE_AGENT) < tgt)
        __builtin_amdgcn_s_sleep(1);
    asm volatile("" ::: "memory");           // no load hoisting above the poll
}

// ---------------------------------------------------------------------------
// Persistent LSTM sequence kernel, round 12: r11 compute geometry +
// producer-group dataflow sync (global barrier removed).
// Grid: 160 blocks x 512 threads (8 waves = 8 k-slices of 80).
// Thread tile 4n x 4b; U k-major in LDS; red[] XOR-swizzled; h published
// via one sc1 store and read as plain L2 loads of per-step-unique addrs.
// r11 post-mortem: TLP=2 changed nothing -> residual was the TLP-invariant
// global-barrier latency chain (drain + sub RMW + master RMW + 160-poller
// detect + cold h fill, ~2-3us serial per step). This round: per-wave
// producer waits (one RMW + one poll), xz prefetch under the wait, and
// hp_epi as a register carry (own block's previous output).
// ---------------------------------------------------------------------------
__global__ __launch_bounds__(512) void lstm_seq_kernel(
    const float* __restrict__ xz,      // [TC][2560][64]
    const float* __restrict__ Upg,     // [160][640][16] pre-transposed (k-major)
    const float* __restrict__ hinit,   // [640][64] carry-in (prev chunk tail / zeros)
    float* __restrict__ c_st,          // [640][64]
    const int* __restrict__ lens,      // [64]
    float* __restrict__ hc_out,        // [TC][640][64]; doubles as h publish chain
    int t0,
    unsigned* __restrict__ arr,        // 8 arrival counters, 128B apart
    unsigned arr_base)                 // bumps before this launch (launch_idx*63)
{
    const int tid  = threadIdx.x;
    const int d0   = blockIdx.x * 4;
    const int ks   = tid >> 6;               // 0..7 (wave = k-slice of 80)
    const int kbeg = ks * 80;
    const int my_grp = blockIdx.x / GRPB;    // arrival group this block feeds
    const int lane   = tid & 63;
    const int n_grp  = lane >> 4;            // 0..3
    const int n_base = n_grp * 4;            // 0,4,8,12
    const int b0     = (lane & 15) * 4;      // 0,4,..,60

    __shared__ float U_lds[640 * 16];        // 40 KB, k-major [k][n16]
    __shared__ float red[128][64];           // 32 KB: [n16*8+ks][b ^ (n_grp<<2)]

    // stage this block's U slice to LDS once (linear 40 KB float4 copy)
    {
        const float4* upg = (const float4*)(Upg + (size_t)blockIdx.x * (640 * 16));
        float4* udst = (float4*)U_lds;
#pragma unroll
        for (int it = 0; it < 5; ++it)
            udst[it * 512 + tid] = upg[it * 512 + tid];
    }

    // epilogue-private state: threads 0..255 own one (d,b) cell
    const bool epi = tid < 256;
    const int ed = d0 + ((tid >> 6) & 3);
    const int eb = tid & 63;
    float c_reg = 0.f, hpe = 0.f;
    int   len_b = 0;
    if (epi) {
        c_reg = c_st[ed * 64 + eb];
        len_b = lens[eb];
        hpe   = hinit[ed * 64 + eb];         // h(t-1)[ed][eb], register-carried
    }

    __syncthreads();                         // U_lds ready

    float acc[16];                           // [i-row 0..3][q-col 0..3]
    float HA[16], HB[16], HC[16];            // 4k x 4b each
    float UA[16], UB[16], UC[16];            // 4k x 4n each

#define HLOAD(HH)                                                           \
    _Pragma("unroll")                                                       \
    for (int j = 0; j < 4; ++j)                                             \
        *(float4*)&HH[j * 4] = *(const float4*)(hrun + j * 64);             \
    hrun += 256;

#define ULOAD(UU)                                                           \
    _Pragma("unroll")                                                       \
    for (int j = 0; j < 4; ++j)                                             \
        *(float4*)&UU[j * 4] = *(const float4*)(urun + j * 16);             \
    urun += 64;

#define FMAG(HH, UU)                                                        \
    _Pragma("unroll")                                                       \
    for (int j = 0; j < 4; ++j)                                             \
        _Pragma("unroll")                                                   \
        for (int i = 0; i < 4; ++i)                                         \
            _Pragma("unroll")                                               \
            for (int q = 0; q < 4; ++q)                                     \
                acc[i * 4 + q] += UU[j * 4 + i] * HH[j * 4 + q];

#pragma unroll 1
    for (int tl = 0; tl < TC; ++tl) {
        const int t = t0 + tl;
        const float* hprev = (tl == 0) ? hinit
                           : hc_out + (size_t)(tl - 1) * (D_ * 64);
        float*       hcur  = hc_out + (size_t)tl * (D_ * 64);

        // xz prefetch BEFORE the wait -> LLC latency hides under the spin
        float xzv[4];
        if (epi) {
            const float* xzp = xz + (size_t)tl * (L4_ * 64) + eb;
#pragma unroll
            for (int g = 0; g < 4; ++g)
                xzv[g] = xzp[(size_t)(ed + 640 * g) * 64];
        }

        // wait for THIS wave's 20 producer blocks to have published h(tl-1)
        if (tl != 0)
            wait_group(arr, ks, GRPB * (arr_base + (unsigned)tl));

#pragma unroll
        for (int i = 0; i < 16; ++i) acc[i] = 0.f;

        const float* hrun = hprev + (size_t)kbeg * 64 + b0;
        const float* urun = &U_lds[(size_t)kbeg * 16 + n_base];

        // 3-stage pipeline over 20 groups of 4 k
        HLOAD(HA) ULOAD(UA)
        HLOAD(HB) ULOAD(UB)
        HLOAD(HC) ULOAD(UC)
#pragma unroll 1
        for (int t3 = 0; t3 < 5; ++t3) {     // computes G0..G14, loads G3..G17
            FMAG(HA, UA) HLOAD(HA) ULOAD(UA)
            FMAG(HB, UB) HLOAD(HB) ULOAD(UB)
            FMAG(HC, UC) HLOAD(HC) ULOAD(UC)
        }
        FMAG(HA, UA) HLOAD(HA) ULOAD(UA)     // G15; load G18
        FMAG(HB, UB) HLOAD(HB) ULOAD(UB)     // G16; load G19
        FMAG(HC, UC)                          // G17
        FMAG(HA, UA)                          // G18
        FMAG(HB, UB)                          // G19

        // partials -> red with XOR-swizzled column
        {
            const int colw = b0 ^ (n_grp << 2);
#pragma unroll
            for (int i = 0; i < 4; ++i)
                *(float4*)&red[((n_base + i) << 3) | ks][colw] = *(float4*)&acc[i * 4];
        }
        __syncthreads();

        if (epi) {
            const int dd = (tid >> 6) & 3;
            const int colr = eb ^ (dd << 2);
            float z[4];
#pragma unroll
            for (int g = 0; g < 4; ++g) {
                const int r = ((dd * 4 + g) << 3);
                float s = 0.f;
#pragma unroll
                for (int kk = 0; kk < 8; ++kk) s += red[r + kk][colr];
                z[g] = s + xzv[g];
            }
            float ig = 1.f / (1.f + __expf(-z[0]));
            float fg = 1.f / (1.f + __expf(-z[1]));
            float gg = tanhf(z[2]);
            float og = 1.f / (1.f + __expf(-z[3]));
            float c_new = fg * c_reg + ig * gg;
            float h_new = og * tanhf(c_new);
            bool msk = t < len_b;
            float h_out = msk ? h_new : hpe;
            c_reg = msk ? c_new : c_reg;
            hpe   = h_out;                        // register carry for next step
            stg_llc(hcur + ed * 64 + eb, h_out);  // single sc1 publish store
        }

        // publish-arrive (skip after last step): drain + block sync + one RMW
        if (tl != TC - 1) {
            asm volatile("s_waitcnt vmcnt(0)" ::: "memory");
            __syncthreads();
            if (tid == 0)
                __hip_atomic_fetch_add(arr + (my_grp << 5), 1u,
                                       __ATOMIC_RELAXED, __HIP_MEMORY_SCOPE_AGENT);
        }
    }
    if (epi) c_st[ed * 64 + eb] = c_reg;     // persist c for next chunk
#undef HLOAD
#undef ULOAD
#undef FMAG
}

// ---------------------------------------------------------------------------
// Transpose chunk h1c [tl][d][b] -> out [b][t0+tl][d]   (unchanged)
// ---------------------------------------------------------------------------
__global__ __launch_bounds__(256) void transpose_kernel(
    const float* __restrict__ h1c, float* __restrict__ out, int t0)
{
    const int tl   = blockIdx.x;
    const int dblk = blockIdx.y;
    __shared__ float tile[64][65];

    const int r  = threadIdx.x >> 2;
    const int cq = threadIdx.x & 3;

    const float* src = h1c + (size_t)tl * (D_ * 64) + (size_t)(dblk * 64 + r) * 64 + cq * 16;
#pragma unroll
    for (int j = 0; j < 4; ++j) {
        float4 v = *(const float4*)(src + j * 4);
        tile[r][cq * 16 + j * 4 + 0] = v.x;
        tile[r][cq * 16 + j * 4 + 1] = v.y;
        tile[r][cq * 16 + j * 4 + 2] = v.z;
        tile[r][cq * 16 + j * 4 + 3] = v.w;
    }
    __syncthreads();

    float* dst = out + (size_t)r * (U_ * D_) + (size_t)(t0 + tl) * D_ + dblk * 64 + cq * 16;
#pragma unroll
    for (int j = 0; j < 4; ++j) {
        float4 w;
        w.x = tile[cq * 16 + j * 4 + 0][r];
        w.y = tile[cq * 16 + j * 4 + 1][r];
        w.z = tile[cq * 16 + j * 4 + 2][r];
        w.w = tile[cq * 16 + j * 4 + 3][r];
        *(float4*)(dst + j * 4) = w;
    }
}

// ---------------------------------------------------------------------------
extern "C" void kernel_launch(void* const* d_in, const int* in_sizes, int n_in,
                              void* d_out, int out_size, void* d_ws, size_t ws_size,
                              hipStream_t stream)
{
    const int*   targets = (const int*)d_in[0];
    const int*   lens    = (const int*)d_in[1];
    const float* embed   = (const float*)d_in[2];
    const float* W0      = (const float*)d_in[3];
    const float* U0      = (const float*)d_in[4];
    const float* b0      = (const float*)d_in[5];
    const float* W1      = (const float*)d_in[6];
    const float* U1      = (const float*)d_in[7];
    const float* b1      = (const float*)d_in[8];
    float* out = (float*)d_out;
    float* ws  = (float*)d_ws;

    // workspace layout (floats)
    float* xz  = ws;                                   // TC*2560*64 = 10,485,760
    float* h0c = xz  + (size_t)TC * L4_ * 64;          // TC*640*64  =  2,621,440
    float* h1c = h0c + (size_t)TC * D_ * 64;           // TC*640*64
    float* st  = h1c + (size_t)TC * D_ * 64;           // 6 * 40,960 state buffers
    float* hzero = st;                                 // zero carry-in for chunk 0
    float* c0  = st + 2 * 40960;
    float* c1  = st + 5 * 40960;
    unsigned* arr = (unsigned*)(st + 6 * 40960);       // 8 arrival lines (128B apart)
    float* Up0 = st + 6 * 40960 + 512;                 // 640*2560 (64B-aligned)
    float* Up1 = Up0 + (size_t)D_ * L4_;               // 640*2560
    // total ~19.25M floats ~= 77 MB (same as verified layout)

    // zero-init states + arrival counters (ws is poisoned before every call)
    hipMemsetAsync(st, 0, (size_t)6 * 40960 * sizeof(float) + 2048, stream);

    // one-time recurrent-weight transpose for both layers (k-major layout)
    prep_up_kernel<<<dim3(D_, 2), dim3(256), 0, stream>>>(U0, U1, Up0, Up1);

    const dim3 gemm_grid(TC * 64 / 128, L4_ / 128);    // (32, 20)
    const dim3 blk(256);
    const dim3 blk_seq(512);

    unsigned launch_idx = 0;
    for (int ch = 0; ch < NCH; ++ch) {
        const int t0 = ch * TC;
        const float* hinit0 = (ch == 0) ? hzero : h0c + (size_t)(TC - 1) * (D_ * 64);
        const float* hinit1 = (ch == 0) ? hzero : h1c + (size_t)(TC - 1) * (D_ * 64);

        // layer 0 input transform: xz = embed[targets] @ W0 + b0
        gemm_kernel<0><<<gemm_grid, blk, 0, stream>>>(embed, targets, W0, b0, xz, E_, t0);

        // layer 0: 64 timesteps in one persistent launch
        lstm_seq_kernel<<<dim3(NBLK), blk_seq, 0, stream>>>(
            xz, Up0, hinit0, c0, lens, h0c, t0, arr, launch_idx * 63u);
        ++launch_idx;

        // layer 1 input transform: xz = h0c @ W1 + b1
        gemm_kernel<1><<<gemm_grid, blk, 0, stream>>>(h0c, targets, W1, b1, xz, D_, t0);

        // layer 1: 64 timesteps in one persistent launch
        lstm_seq_kernel<<<dim3(NBLK), blk_seq, 0, stream>>>(
            xz, Up1, hinit1, c1, lens, h1c, t0, arr, launch_idx * 63u);
        ++launch_idx;

        // emit chunk to output
        transpose_kernel<<<dim3(TC, 10), blk, 0, stream>>>(h1c, out, t0);
    }
}